// Round 6
// baseline (575.069 us; speedup 1.0000x reference)
//
#include <hip/hip_runtime.h>
#include <cstddef>

#define PI2F 6.283185307179586f

typedef __bf16 bf16_t;
typedef __bf16 bf16x8 __attribute__((ext_vector_type(8)));
typedef float f32x4 __attribute__((ext_vector_type(4)));

// ---- workspace layout (float offsets) ----
#define QA_OFF   0u                      // 8,388,608  proj q (later US)
#define KA_OFF   8388608u                // 8,388,608  proj k (later UD)
#define CH_OFF   16777216u               // 33,488,896 chains (later vT, vN)
#define MF_OFF   (CH_OFF + 33488896u)    // 9,437,184  fwd modes
#define MUS_OFF  (MF_OFF + 9437184u)     // 2,359,296  us modes
#define MUD_OFF  (MUS_OFF + 2359296u)    // 2,359,296  ud modes
#define WF_OFF   (MUD_OFF + 2359296u)    // 32,704     fwd twiddles
#define WI_OFF   (WF_OFF + 32704u)       // 32,704     inv twiddles
#define WT_OFF   (WI_OFF + 32704u)       // 786,432 floats = 1.57M bf16 weight tables

// ============================ weight prep: transpose + bf16 split ============================
__global__ __launch_bounds__(256)
void wprep_k(const float* __restrict__ Wq, const float* __restrict__ Wk,
             const float* __restrict__ Wo, bf16_t* __restrict__ WT)
{
    __shared__ float T[32][33];
    const int w = blockIdx.x >> 8;
    const int tile = blockIdx.x & 255;
    const int k0 = (tile & 15) * 32, n0 = (tile >> 4) * 32;
    const float* W = (w == 0) ? Wq : (w == 1) ? Wk : Wo;
    bf16_t* oh = WT + (size_t)w * 524288;
    bf16_t* ol = oh + 262144;
    const int tid = threadIdx.x;
    {
        int row = tid >> 3, q = tid & 7;
        float4 v = *(const float4*)(W + (size_t)(k0 + row) * 512 + n0 + q * 4);
        T[row][q*4+0] = v.x; T[row][q*4+1] = v.y; T[row][q*4+2] = v.z; T[row][q*4+3] = v.w;
    }
    __syncthreads();
    {
        int nr = tid >> 3, q = tid & 7;
        union { bf16_t b[4]; uint2 u; } ph, pl;
#pragma unroll
        for (int j = 0; j < 4; ++j) {
            float x = T[q*4+j][nr];
            bf16_t h = (bf16_t)x;
            ph.b[j] = h;
            pl.b[j] = (bf16_t)(x - (float)h);
        }
        size_t dst = (size_t)(n0 + nr) * 512 + k0 + q * 4;
        *(uint2*)&oh[dst] = ph.u;
        *(uint2*)&ol[dst] = pl.u;
    }
}

// ============================ MFMA split-bf16 GEMM (M=16384, N=512, K=512) ============================
template<bool TOUT>
__global__ __launch_bounds__(256)
void mfma_gemm_k(const float* __restrict__ X, const bf16_t* __restrict__ WTh,
                 const bf16_t* __restrict__ WTl, const float* __restrict__ bias,
                 float* __restrict__ out)
{
    __shared__ __align__(16) char smem[40960];
    bf16_t* Ah = (bf16_t*)smem;          // [128][40]
    bf16_t* Al = Ah + 128 * 40;
    bf16_t* Bh = Al + 128 * 40;
    bf16_t* Bl = Bh + 128 * 40;
    float* Cs = (float*)smem;            // [64][132] epilogue overlay
    const int tid = threadIdx.x;
    const int lane = tid & 63;
    const int wv = tid >> 6;
    const int wm = wv & 1, wn = wv >> 1;
    const int m0 = blockIdx.x << 7, n0 = blockIdx.y << 7;
    const int l15 = lane & 15, quad = lane >> 4;

    f32x4 acc[4][4];
    f32x4 zz = {0.f, 0.f, 0.f, 0.f};
#pragma unroll
    for (int i = 0; i < 4; ++i)
#pragma unroll
        for (int j = 0; j < 4; ++j) acc[i][j] = zz;

    for (int kc = 0; kc < 16; ++kc) {
#pragma unroll
        for (int i = 0; i < 4; ++i) {
            int u = tid + i * 256;
            int row = u >> 3, seg = u & 7;
            float4 v = *(const float4*)(X + (size_t)(m0 + row) * 512 + kc * 32 + seg * 4);
            union { bf16_t b[4]; uint2 u2; } ph, pl;
            float xs[4] = {v.x, v.y, v.z, v.w};
#pragma unroll
            for (int j = 0; j < 4; ++j) {
                bf16_t h = (bf16_t)xs[j];
                ph.b[j] = h;
                pl.b[j] = (bf16_t)(xs[j] - (float)h);
            }
            *(uint2*)&Ah[row * 40 + seg * 4] = ph.u2;
            *(uint2*)&Al[row * 40 + seg * 4] = pl.u2;
        }
#pragma unroll
        for (int i = 0; i < 4; ++i) {
            int u = tid + i * 256;
            int variant = u >> 9;
            int rs = u & 511;
            int row = rs >> 2, seg = rs & 3;
            const bf16_t* src = (variant ? WTl : WTh) + (size_t)(n0 + row) * 512 + kc * 32 + seg * 8;
            bf16_t* dst = (variant ? Bl : Bh) + row * 40 + seg * 8;
            *(float4*)dst = *(const float4*)src;
        }
        __syncthreads();
        bf16x8 ah[4], al[4];
#pragma unroll
        for (int mi = 0; mi < 4; ++mi) {
            int row = wm * 64 + mi * 16 + l15;
            ah[mi] = *(bf16x8*)&Ah[row * 40 + quad * 8];
            al[mi] = *(bf16x8*)&Al[row * 40 + quad * 8];
        }
#pragma unroll
        for (int ni = 0; ni < 4; ++ni) {
            int nr = wn * 64 + ni * 16 + l15;
            bf16x8 bh = *(bf16x8*)&Bh[nr * 40 + quad * 8];
            bf16x8 bl = *(bf16x8*)&Bl[nr * 40 + quad * 8];
#pragma unroll
            for (int mi = 0; mi < 4; ++mi) {
                acc[mi][ni] = __builtin_amdgcn_mfma_f32_16x16x32_bf16(ah[mi], bh, acc[mi][ni], 0, 0, 0);
                acc[mi][ni] = __builtin_amdgcn_mfma_f32_16x16x32_bf16(ah[mi], bl, acc[mi][ni], 0, 0, 0);
                acc[mi][ni] = __builtin_amdgcn_mfma_f32_16x16x32_bf16(al[mi], bh, acc[mi][ni], 0, 0, 0);
            }
        }
        __syncthreads();
    }

    if constexpr (TOUT) {
        const int b8 = (m0 >> 10) * 8, tb = m0 & 1023;
        for (int p = 0; p < 2; ++p) {
            if (wn == p) {
#pragma unroll
                for (int ni = 0; ni < 4; ++ni)
#pragma unroll
                    for (int mi = 0; mi < 4; ++mi)
#pragma unroll
                        for (int r = 0; r < 4; ++r) {
                            int nl = ni * 16 + l15;
                            int m = wm * 64 + mi * 16 + quad * 4 + r;
                            Cs[nl * 132 + m] = acc[mi][ni][r];
                        }
            }
            __syncthreads();
#pragma unroll
            for (int i = 0; i < 8; ++i) {
                int u = tid + i * 256;
                int col = u >> 5, seg = u & 31;
                int gc = n0 + p * 64 + col;
                float bz = bias[gc];
                float4 v = *(float4*)&Cs[col * 132 + seg * 4];
                v.x += bz; v.y += bz; v.z += bz; v.w += bz;
                int h = gc & 7, e = gc >> 3;
                *(float4*)(out + (((size_t)(b8 + h)) * 64 + e) * 1024 + tb + seg * 4) = v;
            }
            __syncthreads();
        }
    } else {
#pragma unroll
        for (int ni = 0; ni < 4; ++ni) {
            int n = n0 + wn * 64 + ni * 16 + l15;
            float bz = bias[n];
#pragma unroll
            for (int mi = 0; mi < 4; ++mi)
#pragma unroll
                for (int r = 0; r < 4; ++r) {
                    int m = m0 + wm * 64 + mi * 16 + quad * 4 + r;
                    out[(size_t)m * 512 + n] = acc[mi][ni][r] + bz;
                }
        }
    }
}

// ============================ twiddle precompute ============================
__global__ __launch_bounds__(256)
void twiddle_k(float* __restrict__ Wf, float* __restrict__ Wi)
{
    int idx = blockIdx.x * 256 + threadIdx.x;
    int table = idx / 32704;
    if (table >= 2) return;
    int r = idx - table * 32704;
    int lvl = 0, base = 0;
    for (int l = 0; l < 9; ++l) {
        int Ll = 512 >> l;
        int sz = 32 * Ll;
        if (r < base + sz) { lvl = l; break; }
        base += sz;
    }
    int L = 512 >> lvl;
    int rr = r - base;
    if (table == 0) {
        int t = rr >> 5, c = rr & 31;
        int j = c & 15, isIm = c >> 4;
        int mv = (j * t) & (L - 1);
        float ang = (PI2F / (float)L) * (float)mv;
        float s, cc; sincosf(ang, &s, &cc);
        Wf[r] = isIm ? -s : cc;
    } else {
        int k = rr / L, t = rr - (rr / L) * L;
        int j = k & 15, isIm = k >> 4;
        int mv = (j * t) & (L - 1);
        float ang = (PI2F / (float)L) * (float)mv;
        float s, cc; sincosf(ang, &s, &cc);
        float scale = 1.f / (4096.f * (float)L);
        float v;
        if (!isIm) v = (j == 0) ? 1.f : 2.f * cc;
        else       v = (j == 0) ? 0.f : -2.f * s;
        Wi[r] = v * scale;
    }
}

// ============================ wavelet chain v2: low-LDS, stream level 0 ============================
// block = (tensor, b, e); 2048 blocks. Level 0 reads global directly (coalesced float2);
// d and s written straight to CH from registers (lane=t -> coalesced); only the s-chain
// lives in LDS (8x520 + 8x264 ping-pong ~ 26 KB -> ~6 blocks/CU vs 2 before).
__global__ __launch_bounds__(256)
void wavelet_chain_k(const float* __restrict__ qin, const float* __restrict__ kin,
                     float* __restrict__ CH,
                     const float* __restrict__ ecd, const float* __restrict__ ecs)
{
    __shared__ float sA[8][520];
    __shared__ float sB[8][264];
    __shared__ float fd[128], fs[128];
    const int tid = threadIdx.x;
    const int tensor = blockIdx.x >> 10;
    const int b = (blockIdx.x >> 6) & 15;
    const int e = blockIdx.x & 63;
    const float* in = tensor ? kin : qin;
    if (tid < 128) fd[tid] = ecd[tid];
    else fs[tid - 128] = ecs[tid - 128];
    __syncthreads();

    const size_t rowd0 = (size_t)((tensor * 2 + 0) * 8192) + (size_t)(b * 8) * 64 + e;

    // ---- level 0: L=512, stream from global ----
    {
        const int L = 512;
#pragma unroll
        for (int it = 0; it < 2; ++it) {
            const int t = tid + it * 256;
            float xa[16];
#pragma unroll
            for (int h = 0; h < 8; ++h) {
                float2 v = *(const float2*)(in + ((size_t)((b*8 + h) * 64 + e)) * 1024 + 2 * t);
                xa[h] = v.x; xa[8 + h] = v.y;
            }
#pragma unroll
            for (int jj = 0; jj < 8; ++jj) {
                float ad = 0.f, as_ = 0.f;
#pragma unroll
                for (int rr = 0; rr < 16; ++rr) {
                    ad  = fmaf(xa[rr], fd[rr * 8 + jj], ad);
                    as_ = fmaf(xa[rr], fs[rr * 8 + jj], as_);
                }
                size_t rowd = rowd0 + (size_t)jj * 64;
                CH[rowd * L + t]          = ad;
                CH[(rowd + 8192) * L + t] = as_;
                sA[jj][t] = as_;
            }
        }
    }
    __syncthreads();

    // ---- levels 1..8 from LDS s-chain ----
    float* cur = &sA[0][0]; int cs = 520;
    float* nxt = &sB[0][0]; int ns = 264;
    for (int lvl = 1; lvl < 9; ++lvl) {
        const int L = 512 >> lvl;
        const size_t chb = (size_t)32768 * (size_t)(1024 - 2 * L);
        if (tid < L) {
            const int t = tid;
            float xa[16];
#pragma unroll
            for (int h = 0; h < 8; ++h) {
                xa[h]     = cur[h * cs + 2 * t];
                xa[8 + h] = cur[h * cs + 2 * t + 1];
            }
#pragma unroll
            for (int jj = 0; jj < 8; ++jj) {
                float ad = 0.f, as_ = 0.f;
#pragma unroll
                for (int rr = 0; rr < 16; ++rr) {
                    ad  = fmaf(xa[rr], fd[rr * 8 + jj], ad);
                    as_ = fmaf(xa[rr], fs[rr * 8 + jj], as_);
                }
                size_t rowd = rowd0 + (size_t)jj * 64;
                CH[chb + rowd * L + t]          = ad;
                CH[chb + (rowd + 8192) * L + t] = as_;
                nxt[jj * ns + t] = as_;
            }
        }
        __syncthreads();
        float* tp = cur; cur = nxt; nxt = tp;
        int ts_ = cs; cs = ns; ns = ts_;
    }
}

// ============================ forward DFT (compute-bound tiling) ============================
__global__ __launch_bounds__(256)
void fwd_dft_k(const float* __restrict__ CH, const float* __restrict__ Wf,
               float* __restrict__ MF)
{
    __shared__ float As[32][132];
    __shared__ float Ws[32][36];
    const int tid = threadIdx.x;
    const int lvl = blockIdx.x >> 8;
    const int tile = blockIdx.x & 255;
    const int L = 512 >> lvl;
    const size_t chb = (size_t)32768 * (size_t)(1024 - 2 * L);
    const int wb = 32 * (1024 - 2 * L);
    const size_t mfb = (size_t)lvl * 1048576;
    const int rowb = tile * 128;
    const int rg = tid >> 3, cg = tid & 7;
    float acc[4][4] = {{0.f}};
    const int kw = (L < 32) ? L : 32;

    for (int k0 = 0; k0 < L; k0 += kw) {
        if (kw >= 4) {
            const int kq = kw >> 2;
            const int kqs = (kq == 8) ? 3 : (kq == 4) ? 2 : (kq == 2) ? 1 : 0;
            const int nf4 = 128 * kq;
            for (int u = tid; u < nf4; u += 256) {
                int row = u >> kqs, q = u & (kq - 1);
                float4 v = *(const float4*)(CH + chb + (size_t)(rowb + row) * L + k0 + q * 4);
                As[q*4+0][row] = v.x; As[q*4+1][row] = v.y;
                As[q*4+2][row] = v.z; As[q*4+3][row] = v.w;
            }
        } else {
            if (tid < 256) {
                int row = tid >> 1, t = tid & 1;
                As[t][row] = CH[chb + (size_t)(rowb + row) * 2 + t];
            }
        }
        for (int u = tid; u < kw * 8; u += 256) {
            int kr = u >> 3, q = u & 7;
            *(float4*)&Ws[kr][q * 4] = *(const float4*)&Wf[wb + (k0 + kr) * 32 + q * 4];
        }
        __syncthreads();
#pragma unroll 4
        for (int kk = 0; kk < kw; ++kk) {
            float4 a4 = *(float4*)&As[kk][rg * 4];
            float4 w4 = *(float4*)&Ws[kk][cg * 4];
            acc[0][0] = fmaf(a4.x, w4.x, acc[0][0]); acc[0][1] = fmaf(a4.x, w4.y, acc[0][1]);
            acc[0][2] = fmaf(a4.x, w4.z, acc[0][2]); acc[0][3] = fmaf(a4.x, w4.w, acc[0][3]);
            acc[1][0] = fmaf(a4.y, w4.x, acc[1][0]); acc[1][1] = fmaf(a4.y, w4.y, acc[1][1]);
            acc[1][2] = fmaf(a4.y, w4.z, acc[1][2]); acc[1][3] = fmaf(a4.y, w4.w, acc[1][3]);
            acc[2][0] = fmaf(a4.z, w4.x, acc[2][0]); acc[2][1] = fmaf(a4.z, w4.y, acc[2][1]);
            acc[2][2] = fmaf(a4.z, w4.z, acc[2][2]); acc[2][3] = fmaf(a4.z, w4.w, acc[2][3]);
            acc[3][0] = fmaf(a4.w, w4.x, acc[3][0]); acc[3][1] = fmaf(a4.w, w4.y, acc[3][1]);
            acc[3][2] = fmaf(a4.w, w4.z, acc[3][2]); acc[3][3] = fmaf(a4.w, w4.w, acc[3][3]);
        }
        __syncthreads();
    }
#pragma unroll
    for (int i = 0; i < 4; ++i) {
        float4 o = {acc[i][0], acc[i][1], acc[i][2], acc[i][3]};
        *(float4*)(MF + mfb + (size_t)(rowb + rg * 4 + i) * 32 + cg * 4) = o;
    }
}

// ============================ combine: S = tanh(QF^T KF), U = S.KF ============================
__global__ __launch_bounds__(256)
void combine2_k(const float* __restrict__ MF, float* __restrict__ MUS, float* __restrict__ MUD)
{
    __shared__ float F[4][64][33];
    __shared__ float Sre[2][16][17], Sim[2][16][17];
    const int tid = threadIdx.x;
    const int lvl = blockIdx.x >> 7;
    const int bh = blockIdx.x & 127;
    const int L = 512 >> lvl;
    const int m = (L / 2 < 16) ? L / 2 : 16;
    const size_t mfb = (size_t)lvl * 1048576;
    for (int a = 0; a < 4; ++a) {
        const float* src = MF + mfb + ((size_t)a * 8192 + (size_t)bh * 64) * 32;
        for (int u = tid; u < 512; u += 256) {
            float4 v = *(const float4*)(src + u * 4);
            int ee = (u * 4) >> 5, c = (u * 4) & 31;
            F[a][ee][c] = v.x; F[a][ee][c+1] = v.y; F[a][ee][c+2] = v.z; F[a][ee][c+3] = v.w;
        }
    }
    __syncthreads();
    const int mm = m * m;
    for (int idx = tid; idx < 2 * mm; idx += 256) {
        int p = idx / mm, rr = idx - p * mm;
        int x = rr / m, y = rr - (rr / m) * m;
        float sr = 0.f, si = 0.f;
        for (int ee = 0; ee < 64; ++ee) {
            float qre = F[p][ee][x],     qim = F[p][ee][16 + x];
            float kre = F[2 + p][ee][y], kim = F[2 + p][ee][16 + y];
            sr = fmaf(qre, kre, sr); sr = fmaf(-qim, kim, sr);
            si = fmaf(qre, kim, si); si = fmaf(qim, kre, si);
        }
        float twoa = fminf(fmaxf(2.f * sr, -30.f), 30.f);
        float e2 = expf(twoa), inv = 1.f / e2;
        float s2b, c2b; sincosf(2.f * si, &s2b, &c2b);
        float den = 0.5f * (e2 + inv) + c2b;
        Sre[p][x][y] = 0.5f * (e2 - inv) / den;
        Sim[p][x][y] = s2b / den;
    }
    __syncthreads();
    for (int idx = tid; idx < 1024; idx += 256) {
        int ee = idx >> 4, x = idx & 15;
        float urd = 0.f, uid = 0.f, urs = 0.f, uis = 0.f;
        if (x < m) {
            for (int y = 0; y < m; ++y) {
                float k0re = F[2][ee][y], k0im = F[2][ee][16 + y];
                float k1re = F[3][ee][y], k1im = F[3][ee][16 + y];
                float s0r = Sre[0][x][y], s0i = Sim[0][x][y];
                float s1r = Sre[1][x][y], s1i = Sim[1][x][y];
                urd = fmaf(s0r, k0re, urd); urd = fmaf(-s0i, k0im, urd);
                uid = fmaf(s0r, k0im, uid); uid = fmaf(s0i, k0re, uid);
                urs = fmaf(s1r, k1re, urs); urs = fmaf(-s1i, k1im, urs);
                uis = fmaf(s1r, k1im, uis); uis = fmaf(s1i, k1re, uis);
            }
        }
        size_t mb = (size_t)lvl * 262144 + ((size_t)bh * 64 + ee) * 32;
        MUS[mb + x]      = urd;
        MUS[mb + 16 + x] = uid;
        MUD[mb + x]      = urd + urs;
        MUD[mb + 16 + x] = uid + uis;
    }
}

// ============================ inverse DFT (compute-bound tiling) ============================
__global__ __launch_bounds__(256)
void inv_dft_k(const float* __restrict__ MUS, const float* __restrict__ MUD,
               const float* __restrict__ Wi,
               float* __restrict__ US, float* __restrict__ UD)
{
    __shared__ float As[32][132];
    __shared__ float Ws[32][36];
    const int bx = blockIdx.x;
    int lvl = 0, base = 0;
#pragma unroll
    for (int l = 0; l < 9; ++l) {
        int cl = 128 << ((l <= 4) ? (4 - l) : 0);
        if (bx < base + cl) { lvl = l; break; }
        base += cl;
    }
    const int r = bx - base;
    const int L = 512 >> lvl;
    const int tcb = (lvl <= 4) ? (4 - lvl) : 0;
    const int tile = r >> tcb;
    const int tc = r & ((1 << tcb) - 1);
    const int t0 = tc * 32;
    const int ar = tile >> 6;
    const int rowb = (tile & 63) * 128;
    const float* MU = ar ? MUD : MUS;
    float* OUT = ar ? UD : US;
    const int wb = 32 * (1024 - 2 * L);
    const size_t uoff = (size_t)8192 * (size_t)(1024 - 2 * L);
    const int nc = (L < 32) ? L : 32;
    const int tid = threadIdx.x;
    const int rg = tid >> 3, cg = tid & 7;

#pragma unroll
    for (int i = 0; i < 4; ++i) {
        int u = tid + i * 256;
        int row = u >> 3, q = u & 7;
        float4 v = *(const float4*)(MU + (size_t)lvl * 262144 + (size_t)(rowb + row) * 32 + q * 4);
        As[q*4+0][row] = v.x; As[q*4+1][row] = v.y;
        As[q*4+2][row] = v.z; As[q*4+3][row] = v.w;
    }
    if (L >= 4) {
        int ncq = nc >> 2;
        int bits = (nc == 32) ? 3 : (nc == 16) ? 2 : (nc == 8) ? 1 : 0;
        for (int u = tid; u < 32 * ncq; u += 256) {
            int kr = u >> bits, q = u & (ncq - 1);
            *(float4*)&Ws[kr][q * 4] = *(const float4*)&Wi[wb + kr * L + t0 + q * 4];
        }
    } else {
        for (int u = tid; u < 64; u += 256)
            Ws[u >> 1][u & 1] = Wi[wb + (u >> 1) * 2 + (u & 1)];
    }
    __syncthreads();
    if (cg * 4 < nc) {
        float acc[4][4] = {{0.f}};
#pragma unroll 8
        for (int kk = 0; kk < 32; ++kk) {
            float4 a4 = *(float4*)&As[kk][rg * 4];
            float4 w4 = *(float4*)&Ws[kk][cg * 4];
            acc[0][0] = fmaf(a4.x, w4.x, acc[0][0]); acc[0][1] = fmaf(a4.x, w4.y, acc[0][1]);
            acc[0][2] = fmaf(a4.x, w4.z, acc[0][2]); acc[0][3] = fmaf(a4.x, w4.w, acc[0][3]);
            acc[1][0] = fmaf(a4.y, w4.x, acc[1][0]); acc[1][1] = fmaf(a4.y, w4.y, acc[1][1]);
            acc[1][2] = fmaf(a4.y, w4.z, acc[1][2]); acc[1][3] = fmaf(a4.y, w4.w, acc[1][3]);
            acc[2][0] = fmaf(a4.z, w4.x, acc[2][0]); acc[2][1] = fmaf(a4.z, w4.y, acc[2][1]);
            acc[2][2] = fmaf(a4.z, w4.z, acc[2][2]); acc[2][3] = fmaf(a4.z, w4.w, acc[2][3]);
            acc[3][0] = fmaf(a4.w, w4.x, acc[3][0]); acc[3][1] = fmaf(a4.w, w4.y, acc[3][1]);
            acc[3][2] = fmaf(a4.w, w4.z, acc[3][2]); acc[3][3] = fmaf(a4.w, w4.w, acc[3][3]);
        }
        if (L >= 4) {
#pragma unroll
            for (int i = 0; i < 4; ++i) {
                float4 o = {acc[i][0], acc[i][1], acc[i][2], acc[i][3]};
                *(float4*)(OUT + uoff + (size_t)(rowb + rg * 4 + i) * L + t0 + cg * 4) = o;
            }
        } else {
#pragma unroll
            for (int i = 0; i < 4; ++i) {
                OUT[uoff + (size_t)(rowb + rg * 4 + i) * 2 + 0] = acc[i][0];
                OUT[uoff + (size_t)(rowb + rg * 4 + i) * 2 + 1] = acc[i][1];
            }
        }
    }
}

// ============================ fully-fused reconstruction chain ============================
__global__ __launch_bounds__(256)
void recon_all_k(const float* __restrict__ USg, const float* __restrict__ UDg,
                 const float* __restrict__ rce, const float* __restrict__ rco,
                 float* __restrict__ vT)
{
    __shared__ float v[8][1032];
    __shared__ float se[16][8];
    __shared__ float so[16][8];
    const int tid = threadIdx.x;
    const int b = blockIdx.x >> 6;
    const int e = blockIdx.x & 63;
    if (tid < 128) se[tid >> 3][tid & 7] = rce[tid];
    else { int u = tid - 128; so[u >> 3][u & 7] = rco[u]; }
    if (tid < 16) v[tid >> 1][tid & 1] = 0.f;
    __syncthreads();

    for (int i = 8; i >= 0; --i) {
        const int L = 512 >> i;
        const size_t uoff = (size_t)8192 * (1024 - 2 * L);
        const int nC = (L + 255) >> 8;
        for (int c = nC - 1; c >= 0; --c) {
            const int t = (c << 8) + tid;
            float a[16];
            const bool act = t < L;
            if (act) {
#pragma unroll
                for (int h = 0; h < 8; ++h) {
                    size_t pgl = uoff + ((size_t)((b*8 + h) * 64 + e)) * (size_t)L + t;
                    a[h]     = v[h][t] + USg[pgl];
                    a[8 + h] = UDg[pgl];
                }
            }
            __syncthreads();
            if (act) {
#pragma unroll
                for (int jj = 0; jj < 8; ++jj) {
                    float ev = 0.f, od = 0.f;
#pragma unroll
                    for (int rr = 0; rr < 16; ++rr) {
                        ev = fmaf(a[rr], se[rr][jj], ev);
                        od = fmaf(a[rr], so[rr][jj], od);
                    }
                    v[jj][2 * t]     = ev;
                    v[jj][2 * t + 1] = od;
                }
            }
            __syncthreads();
        }
    }
    for (int u = tid; u < 2048; u += 256) {
        int h = u >> 8, q4 = u & 255;
        float4 val = *(float4*)&v[h][q4 * 4];
        *(float4*)(vT + ((size_t)((b*8 + h) * 64 + e)) * 1024 + q4 * 4) = val;
    }
}

// ============================ transpose T[b][h][e][t] -> N[b][t][e*8+h] ============================
__global__ __launch_bounds__(256)
void trans_tn_k(const float* __restrict__ vT, float* __restrict__ vN)
{
    __shared__ float Ls[512][17];
    const int b = blockIdx.x >> 6;
    const int t0 = (blockIdx.x & 63) << 4;
    const int tid = threadIdx.x;
#pragma unroll
    for (int it = 0; it < 8; ++it) {
        int u = it * 256 + tid;
        int row = u >> 2, part = u & 3;
        float4 v = *(const float4*)(vT + ((size_t)b * 512 + row) * 1024 + t0 + part * 4);
        Ls[row][part*4+0] = v.x;
        Ls[row][part*4+1] = v.y;
        Ls[row][part*4+2] = v.z;
        Ls[row][part*4+3] = v.w;
    }
    __syncthreads();
#pragma unroll
    for (int it = 0; it < 8; ++it) {
        int u = it * 256 + tid;
        int cq = u & 127, tt = u >> 7;
        int c = cq * 4;
        float4 v;
        v.x = Ls[(((c+0) & 7) << 6) + ((c+0) >> 3)][tt];
        v.y = Ls[(((c+1) & 7) << 6) + ((c+1) >> 3)][tt];
        v.z = Ls[(((c+2) & 7) << 6) + ((c+2) >> 3)][tt];
        v.w = Ls[(((c+3) & 7) << 6) + ((c+3) >> 3)][tt];
        *(float4*)(vN + ((size_t)b * 1024 + t0 + tt) * 512 + c) = v;
    }
}

// ============================ driver ============================
extern "C" void kernel_launch(void* const* d_in, const int* in_sizes, int n_in,
                              void* d_out, int out_size, void* d_ws, size_t ws_size,
                              hipStream_t stream)
{
    const float* q    = (const float*)d_in[0];
    const float* k    = (const float*)d_in[1];
    const float* Lq_w = (const float*)d_in[3];
    const float* Lq_b = (const float*)d_in[4];
    const float* Lk_w = (const float*)d_in[5];
    const float* Lk_b = (const float*)d_in[6];
    const float* outw = (const float*)d_in[9];
    const float* outb = (const float*)d_in[10];
    const float* ec_s = (const float*)d_in[11];
    const float* ec_d = (const float*)d_in[12];
    const float* rc_e = (const float*)d_in[13];
    const float* rc_o = (const float*)d_in[14];

    float* ws = (float*)d_ws;
    float* qA  = ws + QA_OFF;
    float* kA  = ws + KA_OFF;
    float* CH  = ws + CH_OFF;
    float* MF  = ws + MF_OFF;
    float* MUS = ws + MUS_OFF;
    float* MUD = ws + MUD_OFF;
    float* Wf  = ws + WF_OFF;
    float* Wi  = ws + WI_OFF;
    bf16_t* WT = (bf16_t*)(ws + WT_OFF);
    float* vT  = CH;
    float* vN  = CH + 8388608;

    twiddle_k<<<256, 256, 0, stream>>>(Wf, Wi);
    wprep_k<<<768, 256, 0, stream>>>(Lq_w, Lk_w, outw, WT);

    dim3 gg(128, 4);
    mfma_gemm_k<true><<<gg, 256, 0, stream>>>(q, WT, WT + 262144, Lq_b, qA);
    mfma_gemm_k<true><<<gg, 256, 0, stream>>>(k, WT + 524288, WT + 786432, Lk_b, kA);

    wavelet_chain_k<<<2048, 256, 0, stream>>>(qA, kA, CH, ec_d, ec_s);
    fwd_dft_k<<<2304, 256, 0, stream>>>(CH, Wf, MF);
    combine2_k<<<1152, 256, 0, stream>>>(MF, MUS, MUD);
    inv_dft_k<<<4480, 256, 0, stream>>>(MUS, MUD, Wi, qA, kA);
    recon_all_k<<<1024, 256, 0, stream>>>(qA, kA, rc_e, rc_o, vT);
    trans_tn_k<<<1024, 256, 0, stream>>>(vT, vN);
    mfma_gemm_k<false><<<gg, 256, 0, stream>>>(vN, WT + 1048576, WT + 1310720, outb, (float*)d_out);
}

// Round 7
// 486.149 us; speedup vs baseline: 1.1829x; 1.1829x over previous
//
#include <hip/hip_runtime.h>
#include <cstddef>

#define PI2F 6.283185307179586f

typedef __bf16 bf16_t;
typedef __bf16 bf16x8 __attribute__((ext_vector_type(8)));
typedef float f32x4 __attribute__((ext_vector_type(4)));

// ---- workspace layout (float offsets) ----
#define QA_OFF   0u                      // 8,388,608  proj q (later US)
#define KA_OFF   8388608u                // 8,388,608  proj k (later UD)
#define CH_OFF   16777216u               // 33,488,896 chains (later vT, vN)
#define MF_OFF   (CH_OFF + 33488896u)    // 9,437,184  fwd modes
#define MUS_OFF  (MF_OFF + 9437184u)     // 2,359,296  us modes
#define MUD_OFF  (MUS_OFF + 2359296u)    // 2,359,296  ud modes
#define WF_OFF   (MUD_OFF + 2359296u)    // 32,704     fwd twiddles
#define WI_OFF   (WF_OFF + 32704u)       // 32,704     inv twiddles
#define WT_OFF   (WI_OFF + 32704u)       // 786,432 floats = 1.57M bf16 weight tables

// ============================ weight prep: transpose + bf16 split ============================
__global__ __launch_bounds__(256)
void wprep_k(const float* __restrict__ Wq, const float* __restrict__ Wk,
             const float* __restrict__ Wo, bf16_t* __restrict__ WT)
{
    __shared__ float T[32][33];
    const int w = blockIdx.x >> 8;
    const int tile = blockIdx.x & 255;
    const int k0 = (tile & 15) * 32, n0 = (tile >> 4) * 32;
    const float* W = (w == 0) ? Wq : (w == 1) ? Wk : Wo;
    bf16_t* oh = WT + (size_t)w * 524288;
    bf16_t* ol = oh + 262144;
    const int tid = threadIdx.x;
    {
        int row = tid >> 3, q = tid & 7;
        float4 v = *(const float4*)(W + (size_t)(k0 + row) * 512 + n0 + q * 4);
        T[row][q*4+0] = v.x; T[row][q*4+1] = v.y; T[row][q*4+2] = v.z; T[row][q*4+3] = v.w;
    }
    __syncthreads();
    {
        int nr = tid >> 3, q = tid & 7;
        union { bf16_t b[4]; uint2 u; } ph, pl;
#pragma unroll
        for (int j = 0; j < 4; ++j) {
            float x = T[q*4+j][nr];
            bf16_t h = (bf16_t)x;
            ph.b[j] = h;
            pl.b[j] = (bf16_t)(x - (float)h);
        }
        size_t dst = (size_t)(n0 + nr) * 512 + k0 + q * 4;
        *(uint2*)&oh[dst] = ph.u;
        *(uint2*)&ol[dst] = pl.u;
    }
}

// ============================ MFMA split-bf16 GEMM (M=16384, N=512, K=512) ============================
template<bool TOUT>
__global__ __launch_bounds__(256)
void mfma_gemm_k(const float* __restrict__ X, const bf16_t* __restrict__ WTh,
                 const bf16_t* __restrict__ WTl, const float* __restrict__ bias,
                 float* __restrict__ out)
{
    __shared__ __align__(16) char smem[40960];
    bf16_t* Ah = (bf16_t*)smem;          // [128][40]
    bf16_t* Al = Ah + 128 * 40;
    bf16_t* Bh = Al + 128 * 40;
    bf16_t* Bl = Bh + 128 * 40;
    float* Cs = (float*)smem;            // [64][132] epilogue overlay
    const int tid = threadIdx.x;
    const int lane = tid & 63;
    const int wv = tid >> 6;
    const int wm = wv & 1, wn = wv >> 1;
    const int m0 = blockIdx.x << 7, n0 = blockIdx.y << 7;
    const int l15 = lane & 15, quad = lane >> 4;

    f32x4 acc[4][4];
    f32x4 zz = {0.f, 0.f, 0.f, 0.f};
#pragma unroll
    for (int i = 0; i < 4; ++i)
#pragma unroll
        for (int j = 0; j < 4; ++j) acc[i][j] = zz;

    for (int kc = 0; kc < 16; ++kc) {
#pragma unroll
        for (int i = 0; i < 4; ++i) {
            int u = tid + i * 256;
            int row = u >> 3, seg = u & 7;
            float4 v = *(const float4*)(X + (size_t)(m0 + row) * 512 + kc * 32 + seg * 4);
            union { bf16_t b[4]; uint2 u2; } ph, pl;
            float xs[4] = {v.x, v.y, v.z, v.w};
#pragma unroll
            for (int j = 0; j < 4; ++j) {
                bf16_t h = (bf16_t)xs[j];
                ph.b[j] = h;
                pl.b[j] = (bf16_t)(xs[j] - (float)h);
            }
            *(uint2*)&Ah[row * 40 + seg * 4] = ph.u2;
            *(uint2*)&Al[row * 40 + seg * 4] = pl.u2;
        }
#pragma unroll
        for (int i = 0; i < 4; ++i) {
            int u = tid + i * 256;
            int variant = u >> 9;
            int rs = u & 511;
            int row = rs >> 2, seg = rs & 3;
            const bf16_t* src = (variant ? WTl : WTh) + (size_t)(n0 + row) * 512 + kc * 32 + seg * 8;
            bf16_t* dst = (variant ? Bl : Bh) + row * 40 + seg * 8;
            *(float4*)dst = *(const float4*)src;
        }
        __syncthreads();
        bf16x8 ah[4], al[4];
#pragma unroll
        for (int mi = 0; mi < 4; ++mi) {
            int row = wm * 64 + mi * 16 + l15;
            ah[mi] = *(bf16x8*)&Ah[row * 40 + quad * 8];
            al[mi] = *(bf16x8*)&Al[row * 40 + quad * 8];
        }
#pragma unroll
        for (int ni = 0; ni < 4; ++ni) {
            int nr = wn * 64 + ni * 16 + l15;
            bf16x8 bh = *(bf16x8*)&Bh[nr * 40 + quad * 8];
            bf16x8 bl = *(bf16x8*)&Bl[nr * 40 + quad * 8];
#pragma unroll
            for (int mi = 0; mi < 4; ++mi) {
                acc[mi][ni] = __builtin_amdgcn_mfma_f32_16x16x32_bf16(ah[mi], bh, acc[mi][ni], 0, 0, 0);
                acc[mi][ni] = __builtin_amdgcn_mfma_f32_16x16x32_bf16(ah[mi], bl, acc[mi][ni], 0, 0, 0);
                acc[mi][ni] = __builtin_amdgcn_mfma_f32_16x16x32_bf16(al[mi], bh, acc[mi][ni], 0, 0, 0);
            }
        }
        __syncthreads();
    }

    if constexpr (TOUT) {
        const int b8 = (m0 >> 10) * 8, tb = m0 & 1023;
        for (int p = 0; p < 2; ++p) {
            if (wn == p) {
#pragma unroll
                for (int ni = 0; ni < 4; ++ni)
#pragma unroll
                    for (int mi = 0; mi < 4; ++mi)
#pragma unroll
                        for (int r = 0; r < 4; ++r) {
                            int nl = ni * 16 + l15;
                            int m = wm * 64 + mi * 16 + quad * 4 + r;
                            Cs[nl * 132 + m] = acc[mi][ni][r];
                        }
            }
            __syncthreads();
#pragma unroll
            for (int i = 0; i < 8; ++i) {
                int u = tid + i * 256;
                int col = u >> 5, seg = u & 31;
                int gc = n0 + p * 64 + col;
                float bz = bias[gc];
                float4 v = *(float4*)&Cs[col * 132 + seg * 4];
                v.x += bz; v.y += bz; v.z += bz; v.w += bz;
                int h = gc & 7, e = gc >> 3;
                *(float4*)(out + (((size_t)(b8 + h)) * 64 + e) * 1024 + tb + seg * 4) = v;
            }
            __syncthreads();
        }
    } else {
#pragma unroll
        for (int ni = 0; ni < 4; ++ni) {
            int n = n0 + wn * 64 + ni * 16 + l15;
            float bz = bias[n];
#pragma unroll
            for (int mi = 0; mi < 4; ++mi)
#pragma unroll
                for (int r = 0; r < 4; ++r) {
                    int m = m0 + wm * 64 + mi * 16 + quad * 4 + r;
                    out[(size_t)m * 512 + n] = acc[mi][ni][r] + bz;
                }
        }
    }
}

// ============================ twiddle precompute ============================
__global__ __launch_bounds__(256)
void twiddle_k(float* __restrict__ Wf, float* __restrict__ Wi)
{
    int idx = blockIdx.x * 256 + threadIdx.x;
    int table = idx / 32704;
    if (table >= 2) return;
    int r = idx - table * 32704;
    int lvl = 0, base = 0;
    for (int l = 0; l < 9; ++l) {
        int Ll = 512 >> l;
        int sz = 32 * Ll;
        if (r < base + sz) { lvl = l; break; }
        base += sz;
    }
    int L = 512 >> lvl;
    int rr = r - base;
    if (table == 0) {
        int t = rr >> 5, c = rr & 31;
        int j = c & 15, isIm = c >> 4;
        int mv = (j * t) & (L - 1);
        float ang = (PI2F / (float)L) * (float)mv;
        float s, cc; sincosf(ang, &s, &cc);
        Wf[r] = isIm ? -s : cc;
    } else {
        int k = rr / L, t = rr - (rr / L) * L;
        int j = k & 15, isIm = k >> 4;
        int mv = (j * t) & (L - 1);
        float ang = (PI2F / (float)L) * (float)mv;
        float s, cc; sincosf(ang, &s, &cc);
        float scale = 1.f / (4096.f * (float)L);
        float v;
        if (!isIm) v = (j == 0) ? 1.f : 2.f * cc;
        else       v = (j == 0) ? 0.f : -2.f * s;
        Wi[r] = v * scale;
    }
}

// ============================ per-level wavelet (levels with L >= 64) ============================
// block = (tensor, b, e, tc); 256 threads = 64 t x 4 jj-pairs. One float4 load/thread,
// 16 stride-2 LDS reads (2-way aliasing = free), 64 fma, 4 coalesced dword stores.
__global__ __launch_bounds__(256)
void wavelet_lvl_k(const float* __restrict__ in_t0, const float* __restrict__ in_t1,
                   float* __restrict__ CH,
                   const float* __restrict__ ecd, const float* __restrict__ ecs,
                   int L, int inLen, int nt)
{
    __shared__ float sIn[8][132];
    __shared__ float fd[128], fs[128];
    const int tid = threadIdx.x;
    const int col = blockIdx.x / nt;
    const int tc = blockIdx.x - col * nt;
    const int tensor = col >> 10;
    const int b = (col >> 6) & 15;
    const int e = col & 63;
    if (tid < 128) fd[tid] = ecd[tid];
    else fs[tid - 128] = ecs[tid - 128];
    const float* in = tensor ? in_t1 : in_t0;
    {
        int h = tid >> 5, q = tid & 31;
        *(float4*)&sIn[h][q * 4] =
            *(const float4*)(in + (size_t)((b*8 + h) * 64 + e) * (size_t)inLen + tc * 128 + q * 4);
    }
    __syncthreads();
    const int jj2 = tid >> 6, t = tid & 63;
    float xa[16];
#pragma unroll
    for (int h = 0; h < 8; ++h) {
        xa[h]     = sIn[h][2 * t];
        xa[8 + h] = sIn[h][2 * t + 1];
    }
    const size_t rowd0 = (size_t)(tensor * 2) * 8192 + (size_t)(b * 8) * 64 + e;
    const size_t chb = (size_t)32768 * (size_t)(1024 - 2 * L);
    const int tg = tc * 64 + t;
#pragma unroll
    for (int jq = 0; jq < 2; ++jq) {
        int jj = jj2 * 2 + jq;
        float d = 0.f, s = 0.f;
#pragma unroll
        for (int rr = 0; rr < 16; ++rr) {
            d = fmaf(xa[rr], fd[rr * 8 + jj], d);
            s = fmaf(xa[rr], fs[rr * 8 + jj], s);
        }
        size_t rowd = rowd0 + (size_t)jj * 64;
        CH[chb + rowd * (size_t)L + tg]          = d;
        CH[chb + (rowd + 8192) * (size_t)L + tg] = s;
    }
}

// ============================ deep wavelet levels 4..8 (L=32..2), fused ============================
// block = (tensor, b, e); 2048 blocks, tiny LDS -> fully resident.
__global__ __launch_bounds__(256)
void wavelet_deep_k(const float* __restrict__ in_t0, const float* __restrict__ in_t1,
                    float* __restrict__ CH,
                    const float* __restrict__ ecd, const float* __restrict__ ecs)
{
    __shared__ float sP[8][66];
    __shared__ float sN[8][34];
    __shared__ float fd[128], fs[128];
    const int tid = threadIdx.x;
    const int tensor = blockIdx.x >> 10;
    const int b = (blockIdx.x >> 6) & 15;
    const int e = blockIdx.x & 63;
    if (tid < 128) fd[tid] = ecd[tid];
    else fs[tid - 128] = ecs[tid - 128];
    const float* in = tensor ? in_t1 : in_t0;
    if (tid < 128) {
        int h = tid >> 4, q = tid & 15;
        *(float4*)&sP[h][q * 4] =
            *(const float4*)(in + (size_t)((b*8 + h) * 64 + e) * 64 + q * 4);
    }
    __syncthreads();
    float* cur = &sP[0][0]; int cs = 66;
    float* nxt = &sN[0][0]; int ns = 34;
    const size_t rowd0 = (size_t)(tensor * 2) * 8192 + (size_t)(b * 8) * 64 + e;
    for (int lvl = 4; lvl < 9; ++lvl) {
        const int L = 512 >> lvl;
        const size_t chb = (size_t)32768 * (size_t)(1024 - 2 * L);
        if (tid < 8 * L) {
            const int jj = tid / L;
            const int t = tid - jj * L;
            float d = 0.f, s = 0.f;
#pragma unroll
            for (int rr = 0; rr < 16; ++rr) {
                float x = (rr < 8) ? cur[rr * cs + 2 * t] : cur[(rr - 8) * cs + 2 * t + 1];
                d = fmaf(x, fd[rr * 8 + jj], d);
                s = fmaf(x, fs[rr * 8 + jj], s);
            }
            size_t rowd = rowd0 + (size_t)jj * 64;
            CH[chb + rowd * (size_t)L + t]          = d;
            CH[chb + (rowd + 8192) * (size_t)L + t] = s;
            nxt[jj * ns + t] = s;
        }
        __syncthreads();
        float* tp = cur; cur = nxt; nxt = tp;
        int ts_ = cs; cs = ns; ns = ts_;
    }
}

// ============================ forward DFT (compute-bound tiling) ============================
__global__ __launch_bounds__(256)
void fwd_dft_k(const float* __restrict__ CH, const float* __restrict__ Wf,
               float* __restrict__ MF)
{
    __shared__ float As[32][132];
    __shared__ float Ws[32][36];
    const int tid = threadIdx.x;
    const int lvl = blockIdx.x >> 8;
    const int tile = blockIdx.x & 255;
    const int L = 512 >> lvl;
    const size_t chb = (size_t)32768 * (size_t)(1024 - 2 * L);
    const int wb = 32 * (1024 - 2 * L);
    const size_t mfb = (size_t)lvl * 1048576;
    const int rowb = tile * 128;
    const int rg = tid >> 3, cg = tid & 7;
    float acc[4][4] = {{0.f}};
    const int kw = (L < 32) ? L : 32;

    for (int k0 = 0; k0 < L; k0 += kw) {
        if (kw >= 4) {
            const int kq = kw >> 2;
            const int kqs = (kq == 8) ? 3 : (kq == 4) ? 2 : (kq == 2) ? 1 : 0;
            const int nf4 = 128 * kq;
            for (int u = tid; u < nf4; u += 256) {
                int row = u >> kqs, q = u & (kq - 1);
                float4 v = *(const float4*)(CH + chb + (size_t)(rowb + row) * L + k0 + q * 4);
                As[q*4+0][row] = v.x; As[q*4+1][row] = v.y;
                As[q*4+2][row] = v.z; As[q*4+3][row] = v.w;
            }
        } else {
            if (tid < 256) {
                int row = tid >> 1, t = tid & 1;
                As[t][row] = CH[chb + (size_t)(rowb + row) * 2 + t];
            }
        }
        for (int u = tid; u < kw * 8; u += 256) {
            int kr = u >> 3, q = u & 7;
            *(float4*)&Ws[kr][q * 4] = *(const float4*)&Wf[wb + (k0 + kr) * 32 + q * 4];
        }
        __syncthreads();
#pragma unroll 4
        for (int kk = 0; kk < kw; ++kk) {
            float4 a4 = *(float4*)&As[kk][rg * 4];
            float4 w4 = *(float4*)&Ws[kk][cg * 4];
            acc[0][0] = fmaf(a4.x, w4.x, acc[0][0]); acc[0][1] = fmaf(a4.x, w4.y, acc[0][1]);
            acc[0][2] = fmaf(a4.x, w4.z, acc[0][2]); acc[0][3] = fmaf(a4.x, w4.w, acc[0][3]);
            acc[1][0] = fmaf(a4.y, w4.x, acc[1][0]); acc[1][1] = fmaf(a4.y, w4.y, acc[1][1]);
            acc[1][2] = fmaf(a4.y, w4.z, acc[1][2]); acc[1][3] = fmaf(a4.y, w4.w, acc[1][3]);
            acc[2][0] = fmaf(a4.z, w4.x, acc[2][0]); acc[2][1] = fmaf(a4.z, w4.y, acc[2][1]);
            acc[2][2] = fmaf(a4.z, w4.z, acc[2][2]); acc[2][3] = fmaf(a4.z, w4.w, acc[2][3]);
            acc[3][0] = fmaf(a4.w, w4.x, acc[3][0]); acc[3][1] = fmaf(a4.w, w4.y, acc[3][1]);
            acc[3][2] = fmaf(a4.w, w4.z, acc[3][2]); acc[3][3] = fmaf(a4.w, w4.w, acc[3][3]);
        }
        __syncthreads();
    }
#pragma unroll
    for (int i = 0; i < 4; ++i) {
        float4 o = {acc[i][0], acc[i][1], acc[i][2], acc[i][3]};
        *(float4*)(MF + mfb + (size_t)(rowb + rg * 4 + i) * 32 + cg * 4) = o;
    }
}

// ============================ combine: S = tanh(QF^T KF), U = S.KF ============================
__global__ __launch_bounds__(256)
void combine2_k(const float* __restrict__ MF, float* __restrict__ MUS, float* __restrict__ MUD)
{
    __shared__ float F[4][64][33];
    __shared__ float Sre[2][16][17], Sim[2][16][17];
    const int tid = threadIdx.x;
    const int lvl = blockIdx.x >> 7;
    const int bh = blockIdx.x & 127;
    const int L = 512 >> lvl;
    const int m = (L / 2 < 16) ? L / 2 : 16;
    const size_t mfb = (size_t)lvl * 1048576;
    for (int a = 0; a < 4; ++a) {
        const float* src = MF + mfb + ((size_t)a * 8192 + (size_t)bh * 64) * 32;
        for (int u = tid; u < 512; u += 256) {
            float4 v = *(const float4*)(src + u * 4);
            int ee = (u * 4) >> 5, c = (u * 4) & 31;
            F[a][ee][c] = v.x; F[a][ee][c+1] = v.y; F[a][ee][c+2] = v.z; F[a][ee][c+3] = v.w;
        }
    }
    __syncthreads();
    const int mm = m * m;
    for (int idx = tid; idx < 2 * mm; idx += 256) {
        int p = idx / mm, rr = idx - p * mm;
        int x = rr / m, y = rr - (rr / m) * m;
        float sr = 0.f, si = 0.f;
        for (int ee = 0; ee < 64; ++ee) {
            float qre = F[p][ee][x],     qim = F[p][ee][16 + x];
            float kre = F[2 + p][ee][y], kim = F[2 + p][ee][16 + y];
            sr = fmaf(qre, kre, sr); sr = fmaf(-qim, kim, sr);
            si = fmaf(qre, kim, si); si = fmaf(qim, kre, si);
        }
        float twoa = fminf(fmaxf(2.f * sr, -30.f), 30.f);
        float e2 = expf(twoa), inv = 1.f / e2;
        float s2b, c2b; sincosf(2.f * si, &s2b, &c2b);
        float den = 0.5f * (e2 + inv) + c2b;
        Sre[p][x][y] = 0.5f * (e2 - inv) / den;
        Sim[p][x][y] = s2b / den;
    }
    __syncthreads();
    for (int idx = tid; idx < 1024; idx += 256) {
        int ee = idx >> 4, x = idx & 15;
        float urd = 0.f, uid = 0.f, urs = 0.f, uis = 0.f;
        if (x < m) {
            for (int y = 0; y < m; ++y) {
                float k0re = F[2][ee][y], k0im = F[2][ee][16 + y];
                float k1re = F[3][ee][y], k1im = F[3][ee][16 + y];
                float s0r = Sre[0][x][y], s0i = Sim[0][x][y];
                float s1r = Sre[1][x][y], s1i = Sim[1][x][y];
                urd = fmaf(s0r, k0re, urd); urd = fmaf(-s0i, k0im, urd);
                uid = fmaf(s0r, k0im, uid); uid = fmaf(s0i, k0re, uid);
                urs = fmaf(s1r, k1re, urs); urs = fmaf(-s1i, k1im, urs);
                uis = fmaf(s1r, k1im, uis); uis = fmaf(s1i, k1re, uis);
            }
        }
        size_t mb = (size_t)lvl * 262144 + ((size_t)bh * 64 + ee) * 32;
        MUS[mb + x]      = urd;
        MUS[mb + 16 + x] = uid;
        MUD[mb + x]      = urd + urs;
        MUD[mb + 16 + x] = uid + uis;
    }
}

// ============================ inverse DFT (compute-bound tiling) ============================
__global__ __launch_bounds__(256)
void inv_dft_k(const float* __restrict__ MUS, const float* __restrict__ MUD,
               const float* __restrict__ Wi,
               float* __restrict__ US, float* __restrict__ UD)
{
    __shared__ float As[32][132];
    __shared__ float Ws[32][36];
    const int bx = blockIdx.x;
    int lvl = 0, base = 0;
#pragma unroll
    for (int l = 0; l < 9; ++l) {
        int cl = 128 << ((l <= 4) ? (4 - l) : 0);
        if (bx < base + cl) { lvl = l; break; }
        base += cl;
    }
    const int r = bx - base;
    const int L = 512 >> lvl;
    const int tcb = (lvl <= 4) ? (4 - lvl) : 0;
    const int tile = r >> tcb;
    const int tc = r & ((1 << tcb) - 1);
    const int t0 = tc * 32;
    const int ar = tile >> 6;
    const int rowb = (tile & 63) * 128;
    const float* MU = ar ? MUD : MUS;
    float* OUT = ar ? UD : US;
    const int wb = 32 * (1024 - 2 * L);
    const size_t uoff = (size_t)8192 * (size_t)(1024 - 2 * L);
    const int nc = (L < 32) ? L : 32;
    const int tid = threadIdx.x;
    const int rg = tid >> 3, cg = tid & 7;

#pragma unroll
    for (int i = 0; i < 4; ++i) {
        int u = tid + i * 256;
        int row = u >> 3, q = u & 7;
        float4 v = *(const float4*)(MU + (size_t)lvl * 262144 + (size_t)(rowb + row) * 32 + q * 4);
        As[q*4+0][row] = v.x; As[q*4+1][row] = v.y;
        As[q*4+2][row] = v.z; As[q*4+3][row] = v.w;
    }
    if (L >= 4) {
        int ncq = nc >> 2;
        int bits = (nc == 32) ? 3 : (nc == 16) ? 2 : (nc == 8) ? 1 : 0;
        for (int u = tid; u < 32 * ncq; u += 256) {
            int kr = u >> bits, q = u & (ncq - 1);
            *(float4*)&Ws[kr][q * 4] = *(const float4*)&Wi[wb + kr * L + t0 + q * 4];
        }
    } else {
        for (int u = tid; u < 64; u += 256)
            Ws[u >> 1][u & 1] = Wi[wb + (u >> 1) * 2 + (u & 1)];
    }
    __syncthreads();
    if (cg * 4 < nc) {
        float acc[4][4] = {{0.f}};
#pragma unroll 8
        for (int kk = 0; kk < 32; ++kk) {
            float4 a4 = *(float4*)&As[kk][rg * 4];
            float4 w4 = *(float4*)&Ws[kk][cg * 4];
            acc[0][0] = fmaf(a4.x, w4.x, acc[0][0]); acc[0][1] = fmaf(a4.x, w4.y, acc[0][1]);
            acc[0][2] = fmaf(a4.x, w4.z, acc[0][2]); acc[0][3] = fmaf(a4.x, w4.w, acc[0][3]);
            acc[1][0] = fmaf(a4.y, w4.x, acc[1][0]); acc[1][1] = fmaf(a4.y, w4.y, acc[1][1]);
            acc[1][2] = fmaf(a4.y, w4.z, acc[1][2]); acc[1][3] = fmaf(a4.y, w4.w, acc[1][3]);
            acc[2][0] = fmaf(a4.z, w4.x, acc[2][0]); acc[2][1] = fmaf(a4.z, w4.y, acc[2][1]);
            acc[2][2] = fmaf(a4.z, w4.z, acc[2][2]); acc[2][3] = fmaf(a4.z, w4.w, acc[2][3]);
            acc[3][0] = fmaf(a4.w, w4.x, acc[3][0]); acc[3][1] = fmaf(a4.w, w4.y, acc[3][1]);
            acc[3][2] = fmaf(a4.w, w4.z, acc[3][2]); acc[3][3] = fmaf(a4.w, w4.w, acc[3][3]);
        }
        if (L >= 4) {
#pragma unroll
            for (int i = 0; i < 4; ++i) {
                float4 o = {acc[i][0], acc[i][1], acc[i][2], acc[i][3]};
                *(float4*)(OUT + uoff + (size_t)(rowb + rg * 4 + i) * L + t0 + cg * 4) = o;
            }
        } else {
#pragma unroll
            for (int i = 0; i < 4; ++i) {
                OUT[uoff + (size_t)(rowb + rg * 4 + i) * 2 + 0] = acc[i][0];
                OUT[uoff + (size_t)(rowb + rg * 4 + i) * 2 + 1] = acc[i][1];
            }
        }
    }
}

// ============================ fully-fused reconstruction chain ============================
__global__ __launch_bounds__(256)
void recon_all_k(const float* __restrict__ USg, const float* __restrict__ UDg,
                 const float* __restrict__ rce, const float* __restrict__ rco,
                 float* __restrict__ vT)
{
    __shared__ float v[8][1032];
    __shared__ float se[16][8];
    __shared__ float so[16][8];
    const int tid = threadIdx.x;
    const int b = blockIdx.x >> 6;
    const int e = blockIdx.x & 63;
    if (tid < 128) se[tid >> 3][tid & 7] = rce[tid];
    else { int u = tid - 128; so[u >> 3][u & 7] = rco[u]; }
    if (tid < 16) v[tid >> 1][tid & 1] = 0.f;
    __syncthreads();

    for (int i = 8; i >= 0; --i) {
        const int L = 512 >> i;
        const size_t uoff = (size_t)8192 * (1024 - 2 * L);
        const int nC = (L + 255) >> 8;
        for (int c = nC - 1; c >= 0; --c) {
            const int t = (c << 8) + tid;
            float a[16];
            const bool act = t < L;
            if (act) {
#pragma unroll
                for (int h = 0; h < 8; ++h) {
                    size_t pgl = uoff + ((size_t)((b*8 + h) * 64 + e)) * (size_t)L + t;
                    a[h]     = v[h][t] + USg[pgl];
                    a[8 + h] = UDg[pgl];
                }
            }
            __syncthreads();
            if (act) {
#pragma unroll
                for (int jj = 0; jj < 8; ++jj) {
                    float ev = 0.f, od = 0.f;
#pragma unroll
                    for (int rr = 0; rr < 16; ++rr) {
                        ev = fmaf(a[rr], se[rr][jj], ev);
                        od = fmaf(a[rr], so[rr][jj], od);
                    }
                    v[jj][2 * t]     = ev;
                    v[jj][2 * t + 1] = od;
                }
            }
            __syncthreads();
        }
    }
    for (int u = tid; u < 2048; u += 256) {
        int h = u >> 8, q4 = u & 255;
        float4 val = *(float4*)&v[h][q4 * 4];
        *(float4*)(vT + ((size_t)((b*8 + h) * 64 + e)) * 1024 + q4 * 4) = val;
    }
}

// ============================ transpose T[b][h][e][t] -> N[b][t][e*8+h] ============================
__global__ __launch_bounds__(256)
void trans_tn_k(const float* __restrict__ vT, float* __restrict__ vN)
{
    __shared__ float Ls[512][17];
    const int b = blockIdx.x >> 6;
    const int t0 = (blockIdx.x & 63) << 4;
    const int tid = threadIdx.x;
#pragma unroll
    for (int it = 0; it < 8; ++it) {
        int u = it * 256 + tid;
        int row = u >> 2, part = u & 3;
        float4 v = *(const float4*)(vT + ((size_t)b * 512 + row) * 1024 + t0 + part * 4);
        Ls[row][part*4+0] = v.x;
        Ls[row][part*4+1] = v.y;
        Ls[row][part*4+2] = v.z;
        Ls[row][part*4+3] = v.w;
    }
    __syncthreads();
#pragma unroll
    for (int it = 0; it < 8; ++it) {
        int u = it * 256 + tid;
        int cq = u & 127, tt = u >> 7;
        int c = cq * 4;
        float4 v;
        v.x = Ls[(((c+0) & 7) << 6) + ((c+0) >> 3)][tt];
        v.y = Ls[(((c+1) & 7) << 6) + ((c+1) >> 3)][tt];
        v.z = Ls[(((c+2) & 7) << 6) + ((c+2) >> 3)][tt];
        v.w = Ls[(((c+3) & 7) << 6) + ((c+3) >> 3)][tt];
        *(float4*)(vN + ((size_t)b * 1024 + t0 + tt) * 512 + c) = v;
    }
}

// ============================ driver ============================
extern "C" void kernel_launch(void* const* d_in, const int* in_sizes, int n_in,
                              void* d_out, int out_size, void* d_ws, size_t ws_size,
                              hipStream_t stream)
{
    const float* q    = (const float*)d_in[0];
    const float* k    = (const float*)d_in[1];
    const float* Lq_w = (const float*)d_in[3];
    const float* Lq_b = (const float*)d_in[4];
    const float* Lk_w = (const float*)d_in[5];
    const float* Lk_b = (const float*)d_in[6];
    const float* outw = (const float*)d_in[9];
    const float* outb = (const float*)d_in[10];
    const float* ec_s = (const float*)d_in[11];
    const float* ec_d = (const float*)d_in[12];
    const float* rc_e = (const float*)d_in[13];
    const float* rc_o = (const float*)d_in[14];

    float* ws = (float*)d_ws;
    float* qA  = ws + QA_OFF;
    float* kA  = ws + KA_OFF;
    float* CH  = ws + CH_OFF;
    float* MF  = ws + MF_OFF;
    float* MUS = ws + MUS_OFF;
    float* MUD = ws + MUD_OFF;
    float* Wf  = ws + WF_OFF;
    float* Wi  = ws + WI_OFF;
    bf16_t* WT = (bf16_t*)(ws + WT_OFF);
    float* vT  = CH;
    float* vN  = CH + 8388608;

    twiddle_k<<<256, 256, 0, stream>>>(Wf, Wi);
    wprep_k<<<768, 256, 0, stream>>>(Lq_w, Lk_w, outw, WT);

    dim3 gg(128, 4);
    mfma_gemm_k<true><<<gg, 256, 0, stream>>>(q, WT, WT + 262144, Lq_b, qA);
    mfma_gemm_k<true><<<gg, 256, 0, stream>>>(k, WT + 524288, WT + 786432, Lk_b, kA);

    // ---- wavelet: per-level full-parallelism launches ----
    // level 0: inputs qA/kA (row length 1024), L=512
    wavelet_lvl_k<<<16384, 256, 0, stream>>>(qA, kA, CH, ec_d, ec_s, 512, 1024, 8);
    // levels 1..3: input = s-chain of previous level inside CH
    for (int lvl = 1; lvl <= 3; ++lvl) {
        int L = 512 >> lvl;
        int Lp = 2 * L;
        size_t chbp = (size_t)32768 * (size_t)(1024 - 2 * Lp);
        const float* i0 = CH + chbp + (size_t)8192 * Lp;    // tensor 0 s-rows
        const float* i1 = CH + chbp + (size_t)24576 * Lp;   // tensor 1 s-rows
        int nt = L / 64;
        wavelet_lvl_k<<<2048 * nt, 256, 0, stream>>>(i0, i1, CH, ec_d, ec_s, L, Lp, nt);
    }
    // levels 4..8 fused (input = s3)
    {
        size_t chbp = (size_t)32768 * (size_t)(1024 - 128);
        const float* i0 = CH + chbp + (size_t)8192 * 64;
        const float* i1 = CH + chbp + (size_t)24576 * 64;
        wavelet_deep_k<<<2048, 256, 0, stream>>>(i0, i1, CH, ec_d, ec_s);
    }

    fwd_dft_k<<<2304, 256, 0, stream>>>(CH, Wf, MF);
    combine2_k<<<1152, 256, 0, stream>>>(MF, MUS, MUD);
    inv_dft_k<<<4480, 256, 0, stream>>>(MUS, MUD, Wi, qA, kA);
    recon_all_k<<<1024, 256, 0, stream>>>(qA, kA, rc_e, rc_o, vT);
    trans_tn_k<<<1024, 256, 0, stream>>>(vT, vN);
    mfma_gemm_k<false><<<gg, 256, 0, stream>>>(vN, WT + 1048576, WT + 1310720, outb, (float*)d_out);
}